// Round 5
// baseline (111.947 us; speedup 1.0000x reference)
//
#include <hip/hip_runtime.h>
#include <math.h>

#define NN 32
#define CC 512
#define PP 1024   // H*W
#define KK 64
static constexpr float EPS = 1e-12f;

// ---------------- transpose conv_w [K][C] -> wT [C][K] ----------------
__global__ void k_transpose_w(const float* __restrict__ w, float* __restrict__ wT) {
    int i = blockIdx.x * 256 + threadIdx.x;   // over C*K = 32768
    if (i >= CC * KK) return;
    int c = i >> 6, k = i & 63;
    wT[i] = w[k * CC + c];
}

// ---------------- fused pixnorm + logits + softmax over K -> sa [N][K][P] ----------------
// grid: N*16 blocks (64 px), 1024 threads = 16 waves.
// Wave w owns c-slice (32 c); lane = 8px x 8k tile (po=lane&7, ko=lane>>3).
// x,w staged in 128-c double-buffered LDS chunks; sumsq fused into staging;
// cross-wave acc reduction via log2 tree in LDS; wave 0 does softmax + store.
__global__ void __launch_bounds__(1024, 4) k_softmax(
        const float* __restrict__ x, const float* __restrict__ wT,
        const float* __restrict__ bias, float* __restrict__ inv_n,
        float* __restrict__ sa) {
    int b = blockIdx.x;
    int n = b >> 4;
    int p0 = (b & 15) << 6;
    int tid = threadIdx.x;
    int lane = tid & 63;
    int wv = __builtin_amdgcn_readfirstlane(tid >> 6);   // wave id 0..15
    int po = lane & 7, ko = lane >> 3;
    int px4 = tid & 15, crow = tid >> 4;                 // staging coords

    __shared__ __align__(16) float smemf[36928];         // 147712 B
    float* XS   = smemf;               // [2][128][64]
    float* WS   = smemf + 16384;       // [2][128][64]
    float* RED2 = smemf + 32768;       // [1024][4] sumsq partials
    float* REDI = RED2 + 4096;         // [64] inv per px

    const float* xb = x + ((size_t)n * CC) * PP + p0;

    float acc[8][8] = {};
    float4 ssq = make_float4(0.f, 0.f, 0.f, 0.f);
    float4 pf0, pf1, pf2, pf3;

#define PF(ii) do { \
        pf0 = *(const float4*)&xb[(size_t)((ii) * 128 + crow) * PP + px4 * 4]; \
        pf1 = *(const float4*)&xb[(size_t)((ii) * 128 + 64 + crow) * PP + px4 * 4]; \
        pf2 = *(const float4*)&wT[((ii) * 128 + crow) * 64 + px4 * 4]; \
        pf3 = *(const float4*)&wT[((ii) * 128 + 64 + crow) * 64 + px4 * 4]; \
    } while (0)

    PF(0);
    for (int i = 0; i < 4; ++i) {
        __syncthreads();                       // buffer free (chunk i-2 consumed)
        int bo = (i & 1) * 8192;
        *(float4*)&XS[bo + crow * 64 + px4 * 4] = pf0;
        *(float4*)&XS[bo + (crow + 64) * 64 + px4 * 4] = pf1;
        *(float4*)&WS[bo + crow * 64 + px4 * 4] = pf2;
        *(float4*)&WS[bo + (crow + 64) * 64 + px4 * 4] = pf3;
        ssq.x = fmaf(pf0.x, pf0.x, ssq.x); ssq.y = fmaf(pf0.y, pf0.y, ssq.y);
        ssq.z = fmaf(pf0.z, pf0.z, ssq.z); ssq.w = fmaf(pf0.w, pf0.w, ssq.w);
        ssq.x = fmaf(pf1.x, pf1.x, ssq.x); ssq.y = fmaf(pf1.y, pf1.y, ssq.y);
        ssq.z = fmaf(pf1.z, pf1.z, ssq.z); ssq.w = fmaf(pf1.w, pf1.w, ssq.w);
        __syncthreads();                       // staged chunk visible
        if (i < 3) { PF(i + 1); }              // fly during compute
        const float* xrow = XS + bo + (wv * 8) * 64 + po * 8;
        const float* wrow = WS + bo + (wv * 8) * 64 + ko * 8;
#pragma unroll
        for (int ii = 0; ii < 8; ++ii) {
            float4 a0 = *(const float4*)(xrow + ii * 64);
            float4 a1 = *(const float4*)(xrow + ii * 64 + 4);
            float4 b0 = *(const float4*)(wrow + ii * 64);
            float4 b1 = *(const float4*)(wrow + ii * 64 + 4);
            float xv[8] = {a0.x, a0.y, a0.z, a0.w, a1.x, a1.y, a1.z, a1.w};
            float wv8[8] = {b0.x, b0.y, b0.z, b0.w, b1.x, b1.y, b1.z, b1.w};
#pragma unroll
            for (int p = 0; p < 8; ++p)
#pragma unroll
                for (int k = 0; k < 8; ++k)
                    acc[p][k] = fmaf(xv[p], wv8[k], acc[p][k]);
        }
    }
#undef PF

    // sumsq partials -> LDS (separate region; visible after first tree barrier)
    *(float4*)&RED2[tid * 4] = ssq;

    // log2 tree reduction of acc across 16 waves (regions reuse staging LDS)
    for (int step = 8; step >= 1; step >>= 1) {
        __syncthreads();
        if (wv >= step && wv < 2 * step) {
            float* rg = smemf + (wv - step) * 4096 + lane * 4;
#pragma unroll
            for (int s = 0; s < 16; ++s) {
                int p = s >> 1, k4 = (s & 1) * 4;
                *(float4*)&rg[s * 256] =
                    make_float4(acc[p][k4], acc[p][k4 + 1], acc[p][k4 + 2], acc[p][k4 + 3]);
            }
        }
        __syncthreads();
        if (wv < step) {
            const float* rg = smemf + wv * 4096 + lane * 4;
#pragma unroll
            for (int s = 0; s < 16; ++s) {
                int p = s >> 1, k4 = (s & 1) * 4;
                float4 v = *(const float4*)&rg[s * 256];
                acc[p][k4] += v.x; acc[p][k4 + 1] += v.y;
                acc[p][k4 + 2] += v.z; acc[p][k4 + 3] += v.w;
            }
        }
    }

    // per-px inverse norm
    if (tid < 64) {
        int q = tid >> 2, e = tid & 3;
        float s = 0.f;
#pragma unroll 8
        for (int m = 0; m < 64; ++m) s += RED2[(m * 16 + q) * 4 + e];
        float inv = 1.0f / fmaxf(sqrtf(s), EPS);
        inv_n[n * PP + p0 + tid] = inv;
        REDI[tid] = inv;
    }
    __syncthreads();

    if (wv == 0) {
        float4 i0 = *(const float4*)&REDI[po * 8];
        float4 i1 = *(const float4*)&REDI[po * 8 + 4];
        float ivv[8] = {i0.x, i0.y, i0.z, i0.w, i1.x, i1.y, i1.z, i1.w};
        float4 bb0 = *(const float4*)&bias[ko * 8];
        float4 bb1 = *(const float4*)&bias[ko * 8 + 4];
        float bv[8] = {bb0.x, bb0.y, bb0.z, bb0.w, bb1.x, bb1.y, bb1.z, bb1.w};
        float mx[8], sm[8];
#pragma unroll
        for (int p = 0; p < 8; ++p) {
            mx[p] = -1e30f;
#pragma unroll
            for (int k = 0; k < 8; ++k) {
                acc[p][k] = fmaf(acc[p][k], ivv[p], bv[k]);   // logits in-place
                mx[p] = fmaxf(mx[p], acc[p][k]);
            }
        }
#pragma unroll
        for (int p = 0; p < 8; ++p) {
            mx[p] = fmaxf(mx[p], __shfl_xor(mx[p], 8));
            mx[p] = fmaxf(mx[p], __shfl_xor(mx[p], 16));
            mx[p] = fmaxf(mx[p], __shfl_xor(mx[p], 32));
        }
#pragma unroll
        for (int p = 0; p < 8; ++p) {
            sm[p] = 0.f;
#pragma unroll
            for (int k = 0; k < 8; ++k) {
                acc[p][k] = __expf(acc[p][k] - mx[p]);        // e in-place
                sm[p] += acc[p][k];
            }
        }
#pragma unroll
        for (int p = 0; p < 8; ++p) {
            sm[p] += __shfl_xor(sm[p], 8);
            sm[p] += __shfl_xor(sm[p], 16);
            sm[p] += __shfl_xor(sm[p], 32);
            sm[p] = 1.0f / sm[p];
        }
#pragma unroll
        for (int k = 0; k < 8; ++k) {
            float* sp = sa + ((size_t)n * KK + ko * 8 + k) * PP + p0 + po * 8;
            *(float4*)sp = make_float4(acc[0][k] * sm[0], acc[1][k] * sm[1],
                                       acc[2][k] * sm[2], acc[3][k] * sm[3]);
            *(float4*)(sp + 4) = make_float4(acc[4][k] * sm[4], acc[5][k] * sm[5],
                                             acc[6][k] * sm[6], acc[7][k] * sm[7]);
        }
    }
}

// ---------------- S[n][k] = sum_p sa ----------------
__global__ void k_srow(const float* __restrict__ sa, float* __restrict__ S) {
    int r = blockIdx.x * 4 + (threadIdx.x >> 6);
    int lane = threadIdx.x & 63;
    const float* sp = sa + (size_t)r * PP + lane;
    float s = 0.f;
#pragma unroll
    for (int i = 0; i < PP / 64; ++i) s += sp[i * 64];
#pragma unroll
    for (int off = 32; off > 0; off >>= 1) s += __shfl_xor(s, off);
    if (lane == 0) S[r] = s;
}

// ---------------- vlad[n][k][c] = sum_p sa*xnorm - S*cent ----------------
// grid: N*8 blocks (full K=64 x 64-wide C tile), 1024 threads = 4 P-groups x 256
__global__ void __launch_bounds__(1024) k_vlad(
        const float* __restrict__ x, const float* __restrict__ sa,
        const float* __restrict__ inv_n, const float* __restrict__ S,
        const float* __restrict__ cent, float* __restrict__ vlad) {
    int n = blockIdx.x >> 3;
    int c0 = (blockIdx.x & 7) << 6;
    int tid = threadIdx.x;
    int pg = tid >> 8;            // 0..3 p-group
    int t = tid & 255;
    int kq = (t & 15) << 2;
    int cq = (t >> 4) << 2;

    __shared__ float lds[4 * 2 * 32 * 68];   // 69632 bytes
    float* sa_s = lds + pg * (2 * 32 * 68);
    float* x_s  = sa_s + 32 * 68;

    float acc[4][4] = {};
    const float* xb = x + ((size_t)n * CC + c0) * PP;
    const float* sb = sa + (size_t)n * KK * PP;
    const float* ib = inv_n + n * PP;
    int pbase = pg << 8;          // 256 pixels per group

    for (int pt = 0; pt < 256; pt += 32) {
        int p0 = pbase + pt;
        __syncthreads();
        for (int i = t; i < 2048; i += 256) {
            int k = i >> 5, p = i & 31;
            sa_s[p * 68 + k] = sb[(size_t)k * PP + p0 + p];
        }
        for (int i = t; i < 2048; i += 256) {
            int c = i >> 5, p = i & 31;
            x_s[p * 68 + c] = xb[(size_t)c * PP + p0 + p] * ib[p0 + p];
        }
        __syncthreads();
#pragma unroll 4
        for (int p = 0; p < 32; ++p) {
            float4 a = *(const float4*)&sa_s[p * 68 + kq];
            float4 bb = *(const float4*)&x_s[p * 68 + cq];
            float av[4] = {a.x, a.y, a.z, a.w};
            float bv[4] = {bb.x, bb.y, bb.z, bb.w};
#pragma unroll
            for (int i = 0; i < 4; ++i)
#pragma unroll
                for (int j = 0; j < 4; ++j)
                    acc[i][j] = fmaf(av[i], bv[j], acc[i][j]);
        }
    }

    __syncthreads();
    if (pg > 0) {
        float* r = lds + (size_t)(pg - 1) * 4096 + t * 16;
#pragma unroll
        for (int i = 0; i < 4; ++i)
#pragma unroll
            for (int j = 0; j < 4; ++j) r[i * 4 + j] = acc[i][j];
    }
    __syncthreads();
    if (pg == 0) {
#pragma unroll
        for (int g = 0; g < 3; ++g) {
            const float* r = lds + (size_t)g * 4096 + t * 16;
#pragma unroll
            for (int i = 0; i < 4; ++i)
#pragma unroll
                for (int j = 0; j < 4; ++j) acc[i][j] += r[i * 4 + j];
        }
#pragma unroll
        for (int kk = 0; kk < 4; ++kk) {
            float sv = S[n * KK + kq + kk];
            const float* cp = &cent[(size_t)(kq + kk) * CC + c0 + cq];
            float4 cv = *(const float4*)cp;
            float4 o;
            o.x = fmaf(-sv, cv.x, acc[kk][0]);
            o.y = fmaf(-sv, cv.y, acc[kk][1]);
            o.z = fmaf(-sv, cv.z, acc[kk][2]);
            o.w = fmaf(-sv, cv.w, acc[kk][3]);
            *(float4*)&vlad[((size_t)n * KK + kq + kk) * CC + c0 + cq] = o;
        }
    }
}

// ---------------- per-row (n,k) sumsq + inv norm ----------------
__global__ void k_rownorm(const float* __restrict__ vlad, float* __restrict__ rinv,
                          float* __restrict__ rsq) {
    int r = blockIdx.x * 4 + (threadIdx.x >> 6);
    int lane = threadIdx.x & 63;
    const float* vp = vlad + (size_t)r * CC + lane;
    float s = 0.f;
#pragma unroll
    for (int i = 0; i < CC / 64; ++i) {
        float v = vp[i * 64];
        s = fmaf(v, v, s);
    }
#pragma unroll
    for (int off = 32; off > 0; off >>= 1) s += __shfl_xor(s, off);
    if (lane == 0) {
        float iv = 1.0f / fmaxf(sqrtf(s), EPS);
        rinv[r] = iv;
        rsq[r] = s * iv * iv;
    }
}

// ---------------- per-n total inverse norm ----------------
__global__ void k_tot(const float* __restrict__ rsq, float* __restrict__ tinv) {
    int n = blockIdx.x;
    int lane = threadIdx.x;   // 64 threads
    float s = rsq[n * KK + lane];
#pragma unroll
    for (int off = 32; off > 0; off >>= 1) s += __shfl_xor(s, off);
    if (lane == 0) tinv[n] = 1.0f / fmaxf(sqrtf(s), EPS);
}

// ---------------- final scale ----------------
__global__ void k_final(const float* __restrict__ vlad, const float* __restrict__ rinv,
                        const float* __restrict__ tinv, float* __restrict__ out) {
    size_t i4 = (size_t)blockIdx.x * 256 + threadIdx.x;   // over 262144 float4s
    float4 v = ((const float4*)vlad)[i4];
    int row = (int)(i4 >> 7);
    int n = row >> 6;
    float sc = rinv[row] * tinv[n];
    float4 o{v.x * sc, v.y * sc, v.z * sc, v.w * sc};
    ((float4*)out)[i4] = o;
}

extern "C" void kernel_launch(void* const* d_in, const int* in_sizes, int n_in,
                              void* d_out, int out_size, void* d_ws, size_t ws_size,
                              hipStream_t stream) {
    const float* x    = (const float*)d_in[0];
    const float* w    = (const float*)d_in[1];
    const float* bias = (const float*)d_in[2];
    const float* cent = (const float*)d_in[3];
    float* ws = (float*)d_ws;

    float* inv_n = ws;                          // 32768
    float* sa    = inv_n + NN * PP;             // 2097152
    float* S     = sa + (size_t)NN * KK * PP;   // 2048
    float* vlad  = S + NN * KK;                 // 1048576
    float* rinv  = vlad + (size_t)NN * KK * CC; // 2048
    float* rsq   = rinv + NN * KK;              // 2048
    float* tinv  = rsq + NN * KK;               // 32
    float* wT    = tinv + NN;                   // 32768

    float* out = (float*)d_out;

    k_transpose_w<<<dim3(128), dim3(256), 0, stream>>>(w, wT);
    k_softmax<<<dim3(NN * 16), dim3(1024), 0, stream>>>(x, wT, bias, inv_n, sa);
    k_srow<<<dim3(NN * KK / 4), dim3(256), 0, stream>>>(sa, S);
    k_vlad<<<dim3(NN * 8), dim3(1024), 0, stream>>>(x, sa, inv_n, S, cent, vlad);
    k_rownorm<<<dim3(NN * KK / 4), dim3(256), 0, stream>>>(vlad, rinv, rsq);
    k_tot<<<dim3(NN), dim3(64), 0, stream>>>(rsq, tinv);
    k_final<<<dim3(1024), dim3(256), 0, stream>>>(vlad, rinv, tinv, out);
}

// Round 6
// 89.367 us; speedup vs baseline: 1.2527x; 1.2527x over previous
//
#include <hip/hip_runtime.h>
#include <math.h>

#define NN 32
#define CC 512
#define PP 1024   // H*W
#define KK 64
static constexpr float EPS = 1e-12f;

// ---------------- transpose conv_w [K][C] -> wT [C][K] ----------------
__global__ void k_transpose_w(const float* __restrict__ w, float* __restrict__ wT) {
    int i = blockIdx.x * 256 + threadIdx.x;   // over C*K = 32768
    if (i >= CC * KK) return;
    int c = i >> 6, k = i & 63;
    wT[i] = w[k * CC + c];
}

// ---------------- fused pixnorm + logits + softmax over K -> sa [N][K][P] ----------------
// 512 blocks (64 px each), 512 threads = 8 waves.
// Each wave: full 64px x 64k output via 8x8 lane tile (po=lane&7 px-octet,
// ko=lane>>3 k-octet) over a 64-c slice (8 c per 64-c chunk, 8 chunks, dbuf).
// ssq fused into staging; 3-step float2 tree reduce over waves; wave 0 epilogue.
__global__ void __launch_bounds__(512, 2) k_softmax(
        const float* __restrict__ x, const float* __restrict__ wT,
        const float* __restrict__ bias, float* __restrict__ inv_n,
        float* __restrict__ sa) {
    int b = blockIdx.x;
    int n = b >> 4;
    int p0 = (b & 15) << 6;
    int tid = threadIdx.x;
    int lane = tid & 63;
    int wv = __builtin_amdgcn_readfirstlane(tid >> 6);   // 0..7
    int po = lane & 7, ko = lane >> 3;
    int row = tid >> 3;            // staging c-row 0..63
    int col8 = (tid & 7) << 3;     // staging px/k column octet

    __shared__ __align__(16) float smem[17984];   // 71936 B -> 2 blocks/CU
    float* XS = smem;              // [2][64][68]
    float* WS = smem + 8704;       // [2][64][68]
    float* R2 = smem + 17408;      // [8][64] ssq wave partials
    float* RI = smem + 17920;      // [64] inv per px

    const float* xb = x + (size_t)n * CC * PP + p0;

    float acc[8][8] = {};          // [px-elem][k-elem]
    float sq[8] = {};
    float4 px0, px1, pw0, pw1;

#define PFS(i) { \
        const float* xp = xb + (size_t)(((i) << 6) + row) * PP + col8; \
        px0 = *(const float4*)xp; px1 = *(const float4*)(xp + 4); \
        const float* wp = wT + ((((i) << 6) + row) << 6) + col8; \
        pw0 = *(const float4*)wp; pw1 = *(const float4*)(wp + 4); }

    PFS(0);
    for (int i = 0; i < 8; ++i) {
        __syncthreads();
        int bo = (i & 1) * 4352;
        float* xd = XS + bo + row * 68 + col8;
        float* wd = WS + bo + row * 68 + col8;
        *(float4*)xd = px0; *(float4*)(xd + 4) = px1;
        *(float4*)wd = pw0; *(float4*)(wd + 4) = pw1;
        sq[0] = fmaf(px0.x, px0.x, sq[0]);
        sq[1] = fmaf(px0.y, px0.y, sq[1]);
        sq[2] = fmaf(px0.z, px0.z, sq[2]);
        sq[3] = fmaf(px0.w, px0.w, sq[3]);
        sq[4] = fmaf(px1.x, px1.x, sq[4]);
        sq[5] = fmaf(px1.y, px1.y, sq[5]);
        sq[6] = fmaf(px1.z, px1.z, sq[6]);
        sq[7] = fmaf(px1.w, px1.w, sq[7]);
        if (i < 7) { PFS(i + 1); }
        __syncthreads();
        const float* xr = XS + bo + (wv << 3) * 68 + (po << 3);
        const float* wr = WS + bo + (wv << 3) * 68 + (ko << 3);
#pragma unroll
        for (int j = 0; j < 8; ++j) {
            float4 a0 = *(const float4*)(xr + j * 68);
            float4 a1 = *(const float4*)(xr + j * 68 + 4);
            float4 b0 = *(const float4*)(wr + j * 68);
            float4 b1 = *(const float4*)(wr + j * 68 + 4);
            float xv[8] = {a0.x, a0.y, a0.z, a0.w, a1.x, a1.y, a1.z, a1.w};
            float wv8[8] = {b0.x, b0.y, b0.z, b0.w, b1.x, b1.y, b1.z, b1.w};
#pragma unroll
            for (int p = 0; p < 8; ++p)
#pragma unroll
                for (int k = 0; k < 8; ++k)
                    acc[p][k] = fmaf(xv[p], wv8[k], acc[p][k]);
        }
    }
#undef PFS

    // ssq: reduce over ko within wave (lanes sharing po), write wave partial
#pragma unroll
    for (int off = 8; off <= 32; off <<= 1)
#pragma unroll
        for (int j = 0; j < 8; ++j) sq[j] += __shfl_xor(sq[j], off);
    if (ko == 0) {
        *(float4*)&R2[(wv << 6) + (po << 3)] = make_float4(sq[0], sq[1], sq[2], sq[3]);
        *(float4*)&R2[(wv << 6) + (po << 3) + 4] = make_float4(sq[4], sq[5], sq[6], sq[7]);
    }

    // tree reduce acc across 8 waves (regions reuse staging LDS [0,16384))
#pragma unroll
    for (int s = 4; s >= 1; s >>= 1) {
        __syncthreads();
        if (wv >= s && wv < 2 * s) {
            float* rg = smem + (wv - s) * 4096 + lane * 2;
#pragma unroll
            for (int e = 0; e < 32; ++e)
                *(float2*)&rg[e * 128] =
                    make_float2(acc[e >> 2][(e & 3) * 2], acc[e >> 2][(e & 3) * 2 + 1]);
        }
        __syncthreads();
        if (wv < s) {
            const float* rg = smem + wv * 4096 + lane * 2;
#pragma unroll
            for (int e = 0; e < 32; ++e) {
                float2 v = *(const float2*)&rg[e * 128];
                acc[e >> 2][(e & 3) * 2] += v.x;
                acc[e >> 2][(e & 3) * 2 + 1] += v.y;
            }
        }
    }

    __syncthreads();
    if (tid < 64) {
        float s = 0.f;
#pragma unroll
        for (int w8 = 0; w8 < 8; ++w8) s += R2[(w8 << 6) + tid];
        float inv = 1.0f / fmaxf(sqrtf(s), EPS);
        inv_n[n * PP + p0 + tid] = inv;
        RI[tid] = inv;
    }
    __syncthreads();

    if (wv == 0) {
        float4 i0 = *(const float4*)&RI[po << 3];
        float4 i1 = *(const float4*)&RI[(po << 3) + 4];
        float ivv[8] = {i0.x, i0.y, i0.z, i0.w, i1.x, i1.y, i1.z, i1.w};
        float4 bb0 = *(const float4*)&bias[ko << 3];
        float4 bb1 = *(const float4*)&bias[(ko << 3) + 4];
        float bv[8] = {bb0.x, bb0.y, bb0.z, bb0.w, bb1.x, bb1.y, bb1.z, bb1.w};
        float mx[8], sm[8];
#pragma unroll
        for (int p = 0; p < 8; ++p) {
            mx[p] = -1e30f;
#pragma unroll
            for (int k = 0; k < 8; ++k) {
                acc[p][k] = fmaf(acc[p][k], ivv[p], bv[k]);   // logits in-place
                mx[p] = fmaxf(mx[p], acc[p][k]);
            }
        }
#pragma unroll
        for (int p = 0; p < 8; ++p) {
            mx[p] = fmaxf(mx[p], __shfl_xor(mx[p], 8));
            mx[p] = fmaxf(mx[p], __shfl_xor(mx[p], 16));
            mx[p] = fmaxf(mx[p], __shfl_xor(mx[p], 32));
        }
#pragma unroll
        for (int p = 0; p < 8; ++p) {
            sm[p] = 0.f;
#pragma unroll
            for (int k = 0; k < 8; ++k) {
                acc[p][k] = __expf(acc[p][k] - mx[p]);        // e in-place
                sm[p] += acc[p][k];
            }
        }
#pragma unroll
        for (int p = 0; p < 8; ++p) {
            sm[p] += __shfl_xor(sm[p], 8);
            sm[p] += __shfl_xor(sm[p], 16);
            sm[p] += __shfl_xor(sm[p], 32);
            sm[p] = 1.0f / sm[p];
        }
#pragma unroll
        for (int k = 0; k < 8; ++k) {
            float* sp = sa + ((size_t)n * KK + (ko << 3) + k) * PP + p0 + (po << 3);
            *(float4*)sp = make_float4(acc[0][k] * sm[0], acc[1][k] * sm[1],
                                       acc[2][k] * sm[2], acc[3][k] * sm[3]);
            *(float4*)(sp + 4) = make_float4(acc[4][k] * sm[4], acc[5][k] * sm[5],
                                             acc[6][k] * sm[6], acc[7][k] * sm[7]);
        }
    }
}

// ---------------- S[n][k] = sum_p sa ----------------
__global__ void k_srow(const float* __restrict__ sa, float* __restrict__ S) {
    int r = blockIdx.x * 4 + (threadIdx.x >> 6);
    int lane = threadIdx.x & 63;
    const float* sp = sa + (size_t)r * PP + lane;
    float s = 0.f;
#pragma unroll
    for (int i = 0; i < PP / 64; ++i) s += sp[i * 64];
#pragma unroll
    for (int off = 32; off > 0; off >>= 1) s += __shfl_xor(s, off);
    if (lane == 0) S[r] = s;
}

// ---------------- vlad[n][k][c] = sum_p sa*xnorm - S*cent ----------------
// 256 blocks (n x 64-c tile), 512 threads = 8 waves.
// Each wave: full 64k x 64c via 8x8 lane tile over a p-slice (8 p per 64-p
// chunk, 16 chunks, dbuf). Staging transposes [.][p] -> [p][.] with XOR
// octet swizzle k' = k ^ ((p>>3&7)<<3) (conflict-free stores AND reads).
__global__ void __launch_bounds__(512, 2) k_vlad(
        const float* __restrict__ x, const float* __restrict__ sa,
        const float* __restrict__ inv_n, const float* __restrict__ S,
        const float* __restrict__ cent, float* __restrict__ vlad) {
    int nb = blockIdx.x >> 3;
    int c0 = (blockIdx.x & 7) << 6;
    int tid = threadIdx.x;
    int lane = tid & 63;
    int wv = __builtin_amdgcn_readfirstlane(tid >> 6);   // 0..7
    int ko = lane & 7, co = lane >> 3;
    int r8 = lane & 7;
    int m  = lane >> 3;
    int krow = (wv << 3) + r8;     // staged k row == staged c row (within tile)
    int pcol8 = m << 3;

    __shared__ __align__(16) float smem[16384];   // 65536 B
    float* SAS = smem;             // [2][64][64]  [p][k']
    float* XSS = smem + 8192;      // [2][64][64]  [p][c']

    const float* sb = sa + (size_t)nb * KK * PP;
    const float* xb = x + ((size_t)nb * CC + c0) * PP;
    const float* ib = inv_n + nb * PP;

    float acc[8][8] = {};          // [k-elem][c-elem]
    float sv[8], xv[8];

#define PFV(i) { \
        const float* sp = sb + (size_t)krow * PP + ((i) << 6) + pcol8; \
        float4 s0 = *(const float4*)sp, s1 = *(const float4*)(sp + 4); \
        const float* xp = xb + (size_t)krow * PP + ((i) << 6) + pcol8; \
        float4 v0 = *(const float4*)xp, v1 = *(const float4*)(xp + 4); \
        const float* ip = ib + ((i) << 6) + pcol8; \
        float4 w0 = *(const float4*)ip, w1 = *(const float4*)(ip + 4); \
        sv[0]=s0.x; sv[1]=s0.y; sv[2]=s0.z; sv[3]=s0.w; \
        sv[4]=s1.x; sv[5]=s1.y; sv[6]=s1.z; sv[7]=s1.w; \
        xv[0]=v0.x*w0.x; xv[1]=v0.y*w0.y; xv[2]=v0.z*w0.z; xv[3]=v0.w*w0.w; \
        xv[4]=v1.x*w1.x; xv[5]=v1.y*w1.y; xv[6]=v1.z*w1.z; xv[7]=v1.w*w1.w; }

    PFV(0);
    for (int i = 0; i < 16; ++i) {
        __syncthreads();
        int bo = (i & 1) << 12;
        int kx = krow ^ (m << 3);
#pragma unroll
        for (int j = 0; j < 8; ++j) {
            SAS[bo + ((pcol8 + j) << 6) + kx] = sv[j];
            XSS[bo + ((pcol8 + j) << 6) + kx] = xv[j];
        }
        if (i < 15) { PFV(i + 1); }
        __syncthreads();
        const float* sr = SAS + bo + ((wv << 3) << 6) + ((ko << 3) ^ (wv << 3));
        const float* xr = XSS + bo + ((wv << 3) << 6) + ((co << 3) ^ (wv << 3));
#pragma unroll
        for (int jj = 0; jj < 8; ++jj) {
            float4 a0 = *(const float4*)(sr + (jj << 6));
            float4 a1 = *(const float4*)(sr + (jj << 6) + 4);
            float4 b0 = *(const float4*)(xr + (jj << 6));
            float4 b1 = *(const float4*)(xr + (jj << 6) + 4);
            float av[8] = {a0.x, a0.y, a0.z, a0.w, a1.x, a1.y, a1.z, a1.w};
            float bw[8] = {b0.x, b0.y, b0.z, b0.w, b1.x, b1.y, b1.z, b1.w};
#pragma unroll
            for (int ii = 0; ii < 8; ++ii)
#pragma unroll
                for (int j = 0; j < 8; ++j)
                    acc[ii][j] = fmaf(av[ii], bw[j], acc[ii][j]);
        }
    }
#undef PFV

    // tree reduce acc across 8 waves (regions = whole smem)
#pragma unroll
    for (int s = 4; s >= 1; s >>= 1) {
        __syncthreads();
        if (wv >= s && wv < 2 * s) {
            float* rg = smem + (wv - s) * 4096 + lane * 2;
#pragma unroll
            for (int e = 0; e < 32; ++e)
                *(float2*)&rg[e * 128] =
                    make_float2(acc[e >> 2][(e & 3) * 2], acc[e >> 2][(e & 3) * 2 + 1]);
        }
        __syncthreads();
        if (wv < s) {
            const float* rg = smem + wv * 4096 + lane * 2;
#pragma unroll
            for (int e = 0; e < 32; ++e) {
                float2 v = *(const float2*)&rg[e * 128];
                acc[e >> 2][(e & 3) * 2] += v.x;
                acc[e >> 2][(e & 3) * 2 + 1] += v.y;
            }
        }
    }

    if (wv == 0) {
#pragma unroll
        for (int ii = 0; ii < 8; ++ii) {
            int k = (ko << 3) + ii;
            float sval = S[nb * KK + k];
            const float* cp = cent + (size_t)k * CC + c0 + (co << 3);
            float4 cv0 = *(const float4*)cp, cv1 = *(const float4*)(cp + 4);
            float4 o0 = make_float4(fmaf(-sval, cv0.x, acc[ii][0]),
                                    fmaf(-sval, cv0.y, acc[ii][1]),
                                    fmaf(-sval, cv0.z, acc[ii][2]),
                                    fmaf(-sval, cv0.w, acc[ii][3]));
            float4 o1 = make_float4(fmaf(-sval, cv1.x, acc[ii][4]),
                                    fmaf(-sval, cv1.y, acc[ii][5]),
                                    fmaf(-sval, cv1.z, acc[ii][6]),
                                    fmaf(-sval, cv1.w, acc[ii][7]));
            float* vp = vlad + ((size_t)nb * KK + k) * CC + c0 + (co << 3);
            *(float4*)vp = o0; *(float4*)(vp + 4) = o1;
        }
    }
}

// ---------------- per-row (n,k) sumsq + inv norm ----------------
__global__ void k_rownorm(const float* __restrict__ vlad, float* __restrict__ rinv,
                          float* __restrict__ rsq) {
    int r = blockIdx.x * 4 + (threadIdx.x >> 6);
    int lane = threadIdx.x & 63;
    const float* vp = vlad + (size_t)r * CC + lane;
    float s = 0.f;
#pragma unroll
    for (int i = 0; i < CC / 64; ++i) {
        float v = vp[i * 64];
        s = fmaf(v, v, s);
    }
#pragma unroll
    for (int off = 32; off > 0; off >>= 1) s += __shfl_xor(s, off);
    if (lane == 0) {
        float iv = 1.0f / fmaxf(sqrtf(s), EPS);
        rinv[r] = iv;
        rsq[r] = s * iv * iv;
    }
}

// ---------------- per-n total inverse norm ----------------
__global__ void k_tot(const float* __restrict__ rsq, float* __restrict__ tinv) {
    int n = blockIdx.x;
    int lane = threadIdx.x;   // 64 threads
    float s = rsq[n * KK + lane];
#pragma unroll
    for (int off = 32; off > 0; off >>= 1) s += __shfl_xor(s, off);
    if (lane == 0) tinv[n] = 1.0f / fmaxf(sqrtf(s), EPS);
}

// ---------------- final scale ----------------
__global__ void k_final(const float* __restrict__ vlad, const float* __restrict__ rinv,
                        const float* __restrict__ tinv, float* __restrict__ out) {
    size_t i4 = (size_t)blockIdx.x * 256 + threadIdx.x;   // over 262144 float4s
    float4 v = ((const float4*)vlad)[i4];
    int row = (int)(i4 >> 7);
    int n = row >> 6;
    float sc = rinv[row] * tinv[n];
    float4 o{v.x * sc, v.y * sc, v.z * sc, v.w * sc};
    ((float4*)out)[i4] = o;
}

extern "C" void kernel_launch(void* const* d_in, const int* in_sizes, int n_in,
                              void* d_out, int out_size, void* d_ws, size_t ws_size,
                              hipStream_t stream) {
    const float* x    = (const float*)d_in[0];
    const float* w    = (const float*)d_in[1];
    const float* bias = (const float*)d_in[2];
    const float* cent = (const float*)d_in[3];
    float* ws = (float*)d_ws;

    float* inv_n = ws;                          // 32768
    float* sa    = inv_n + NN * PP;             // 2097152
    float* S     = sa + (size_t)NN * KK * PP;   // 2048
    float* vlad  = S + NN * KK;                 // 1048576
    float* rinv  = vlad + (size_t)NN * KK * CC; // 2048
    float* rsq   = rinv + NN * KK;              // 2048
    float* tinv  = rsq + NN * KK;               // 32
    float* wT    = tinv + NN;                   // 32768

    float* out = (float*)d_out;

    k_transpose_w<<<dim3(128), dim3(256), 0, stream>>>(w, wT);
    k_softmax<<<dim3(NN * 16), dim3(512), 0, stream>>>(x, wT, bias, inv_n, sa);
    k_srow<<<dim3(NN * KK / 4), dim3(256), 0, stream>>>(sa, S);
    k_vlad<<<dim3(NN * 8), dim3(512), 0, stream>>>(x, sa, inv_n, S, cent, vlad);
    k_rownorm<<<dim3(NN * KK / 4), dim3(256), 0, stream>>>(vlad, rinv, rsq);
    k_tot<<<dim3(NN), dim3(64), 0, stream>>>(rsq, tinv);
    k_final<<<dim3(1024), dim3(256), 0, stream>>>(vlad, rinv, tinv, out);
}

// Round 7
// 69.886 us; speedup vs baseline: 1.6019x; 1.2788x over previous
//
#include <hip/hip_runtime.h>
#include <math.h>

#define NN 32
#define CC 512
#define PP 1024   // H*W
#define KK 64
static constexpr float EPS = 1e-12f;

typedef __attribute__((ext_vector_type(8))) short bf16x8;
typedef __attribute__((ext_vector_type(4))) float f32x4;
typedef __attribute__((ext_vector_type(4))) unsigned int u32x4;
union FragU { u32x4 u; bf16x8 h; };

// pack two fp32 into one u32 of 2 bf16 (RNE)
__device__ __forceinline__ unsigned int bfpair(float lo, float hi) {
    unsigned int ul = __builtin_bit_cast(unsigned int, lo);
    unsigned int uh = __builtin_bit_cast(unsigned int, hi);
    ul = ul + 0x7FFFu + ((ul >> 16) & 1u);
    uh = uh + 0x7FFFu + ((uh >> 16) & 1u);
    return (ul >> 16) | (uh & 0xFFFF0000u);
}

// ---------------- w [K][C] fp32 -> wpk [K][C/2] u32 (bf16 pairs, k-major) ----------------
__global__ void k_wprep(const float* __restrict__ w, unsigned int* __restrict__ wpk) {
    int i = blockIdx.x * 256 + threadIdx.x;   // over K*C/2 = 16384
    wpk[i] = bfpair(w[2 * i], w[2 * i + 1]);
}

// ---------------- fused pixnorm + logits(MFMA) + softmax -> sa [N][K][P] ----------------
// grid: 256 blocks = n(32) x 128-px tile(8). 512 threads = 8 waves.
// Orientation: D[k][px] = sum_c W[k][c] * X[c][px].  A = W (LDS, bf16 pairs,
// whole 64x512 resident), B = X-transposed (LDS [128px][33 cpair] per 64-c chunk,
// double buffered). Wave w owns px-tile pt=w and all 4 k-tiles -> k-softmax is
// in-lane + shfl_xor(16,32). ssq fused into staging; inv applied in fp32 epilogue.
__global__ void __launch_bounds__(512, 2) k_logits(
        const float* __restrict__ x, const unsigned int* __restrict__ wpk,
        const float* __restrict__ bias, float* __restrict__ inv_n,
        float* __restrict__ sa) {
    int b = blockIdx.x;
    int n = b >> 3;
    int p0 = (b & 7) << 7;           // 128-px tile base
    int tid = threadIdx.x;
    int lane = tid & 63;
    int wv = __builtin_amdgcn_readfirstlane(tid >> 6);   // 0..7 = px tile
    int l15 = lane & 15, l4 = lane >> 4;
    int rp = tid >> 4;               // staging cpair row 0..31
    int px8 = (tid & 15) << 3;       // staging px octet

    __shared__ unsigned int smem_u[26240];   // 104960 B
    unsigned int* XP  = smem_u;              // 2 x [128][33] u32
    unsigned int* WBF = smem_u + 8448;       // [64][260] u32 (256 used + pad 4)
    float* RED  = (float*)(smem_u + 25088);  // [8][128] ssq partials
    float* REDI = (float*)(smem_u + 26112);  // [128] inv per px

    // ---- stage whole W (bf16 pairs) into LDS once ----
    {
        int k = tid >> 3, cb = (tid & 7) << 5;
#pragma unroll
        for (int i = 0; i < 8; ++i) {
            u32x4 v = *(const u32x4*)&wpk[(k << 8) + cb + (i << 2)];
            *(u32x4*)&WBF[k * 260 + cb + (i << 2)] = v;
        }
    }

    const float* xb = x + (size_t)n * CC * PP + p0;

    f32x4 c0v = {0.f, 0.f, 0.f, 0.f};
    f32x4 c1v = {0.f, 0.f, 0.f, 0.f};
    f32x4 c2v = {0.f, 0.f, 0.f, 0.f};
    f32x4 c3v = {0.f, 0.f, 0.f, 0.f};
    float ssq[8] = {};
    float4 a0, a1, b0, b1;

#define PFL(i) { const float* xa = xb + (size_t)((i) * 64 + 2 * rp) * PP + px8; \
        a0 = *(const float4*)xa; a1 = *(const float4*)(xa + 4); \
        b0 = *(const float4*)(xa + PP); b1 = *(const float4*)(xa + PP + 4); }

#define MSTEP(H) { \
        FragU bfr; \
        int ob = xo + ((H) << 4); \
        bfr.u[0] = xq[ob]; bfr.u[1] = xq[ob + 1]; \
        bfr.u[2] = xq[ob + 2]; bfr.u[3] = xq[ob + 3]; \
        int oa = l15 * 260 + (i << 5) + ((H) << 4) + (l4 << 2); \
        FragU af; \
        af.u = *(const u32x4*)&WBF[oa]; \
        c0v = __builtin_amdgcn_mfma_f32_16x16x32_bf16(af.h, bfr.h, c0v, 0, 0, 0); \
        af.u = *(const u32x4*)&WBF[oa + 4160]; \
        c1v = __builtin_amdgcn_mfma_f32_16x16x32_bf16(af.h, bfr.h, c1v, 0, 0, 0); \
        af.u = *(const u32x4*)&WBF[oa + 8320]; \
        c2v = __builtin_amdgcn_mfma_f32_16x16x32_bf16(af.h, bfr.h, c2v, 0, 0, 0); \
        af.u = *(const u32x4*)&WBF[oa + 12480]; \
        c3v = __builtin_amdgcn_mfma_f32_16x16x32_bf16(af.h, bfr.h, c3v, 0, 0, 0); \
    }

    PFL(0);
#pragma unroll 1
    for (int i = 0; i < 8; ++i) {
        __syncthreads();   // buffer free + (i==0) WBF visible
        unsigned int* xp = XP + (i & 1) * 4224;
        float av[8] = {a0.x, a0.y, a0.z, a0.w, a1.x, a1.y, a1.z, a1.w};
        float bv[8] = {b0.x, b0.y, b0.z, b0.w, b1.x, b1.y, b1.z, b1.w};
#pragma unroll
        for (int j = 0; j < 8; ++j) {
            xp[(px8 + j) * 33 + rp] = bfpair(av[j], bv[j]);
            ssq[j] = fmaf(av[j], av[j], fmaf(bv[j], bv[j], ssq[j]));
        }
        if (i < 7) { PFL(i + 1); }
        __syncthreads();   // staged chunk visible
        const unsigned int* xq = XP + (i & 1) * 4224;
        int xo = (wv * 16 + l15) * 33 + (l4 << 2);
        MSTEP(0);
        MSTEP(1);
    }
#undef PFL
#undef MSTEP

    // ---- per-px ssq -> inv ----
#pragma unroll
    for (int j = 0; j < 8; ++j) {
        ssq[j] += __shfl_xor(ssq[j], 16);
        ssq[j] += __shfl_xor(ssq[j], 32);
    }
    if (l4 == 0) {
#pragma unroll
        for (int j = 0; j < 8; ++j) RED[(wv << 7) + px8 + j] = ssq[j];
    }
    __syncthreads();
    if (tid < 128) {
        float s = 0.f;
#pragma unroll
        for (int w8 = 0; w8 < 8; ++w8) s += RED[(w8 << 7) + tid];
        float inv = 1.0f / fmaxf(sqrtf(s), EPS);
        inv_n[n * PP + p0 + tid] = inv;
        REDI[tid] = inv;
    }
    __syncthreads();

    // ---- softmax over 64 k (in-lane 16 + shfl over l4) ----
    float inv = REDI[(wv << 4) + l15];
    float lg[16];
#pragma unroll
    for (int r = 0; r < 4; ++r) {
        lg[r]      = c0v[r];
        lg[4 + r]  = c1v[r];
        lg[8 + r]  = c2v[r];
        lg[12 + r] = c3v[r];
    }
    float m = -1e30f;
#pragma unroll
    for (int kk = 0; kk < 16; ++kk) {
        int k = ((kk >> 2) << 4) + (l4 << 2) + (kk & 3);
        lg[kk] = fmaf(lg[kk], inv, bias[k]);
        m = fmaxf(m, lg[kk]);
    }
    m = fmaxf(m, __shfl_xor(m, 16));
    m = fmaxf(m, __shfl_xor(m, 32));
    float sm = 0.f;
#pragma unroll
    for (int kk = 0; kk < 16; ++kk) {
        lg[kk] = __expf(lg[kk] - m);
        sm += lg[kk];
    }
    sm += __shfl_xor(sm, 16);
    sm += __shfl_xor(sm, 32);
    float si = 1.0f / sm;
    float* sp = sa + (size_t)n * KK * PP + p0 + (wv << 4) + l15;
#pragma unroll
    for (int kk = 0; kk < 16; ++kk) {
        int k = ((kk >> 2) << 4) + (l4 << 2) + (kk & 3);
        sp[(size_t)k * PP] = lg[kk] * si;
    }
}

// ---------------- S[n][k] = sum_p sa ----------------
__global__ void k_srow(const float* __restrict__ sa, float* __restrict__ S) {
    int r = blockIdx.x * 4 + (threadIdx.x >> 6);
    int lane = threadIdx.x & 63;
    const float* sp = sa + (size_t)r * PP + lane;
    float s = 0.f;
#pragma unroll
    for (int i = 0; i < PP / 64; ++i) s += sp[i * 64];
#pragma unroll
    for (int off = 32; off > 0; off >>= 1) s += __shfl_xor(s, off);
    if (lane == 0) S[r] = s;
}

// ---------------- vlad[n][k][c] = sum_p sa*xnorm - S*cent ----------------
// 256 blocks (n x 64-c tile), 512 threads = 8 waves. (unchanged from round 6)
__global__ void __launch_bounds__(512, 2) k_vlad(
        const float* __restrict__ x, const float* __restrict__ sa,
        const float* __restrict__ inv_n, const float* __restrict__ S,
        const float* __restrict__ cent, float* __restrict__ vlad) {
    int nb = blockIdx.x >> 3;
    int c0 = (blockIdx.x & 7) << 6;
    int tid = threadIdx.x;
    int lane = tid & 63;
    int wv = __builtin_amdgcn_readfirstlane(tid >> 6);   // 0..7
    int ko = lane & 7, co = lane >> 3;
    int r8 = lane & 7;
    int m  = lane >> 3;
    int krow = (wv << 3) + r8;
    int pcol8 = m << 3;

    __shared__ __align__(16) float smem[16384];   // 65536 B
    float* SAS = smem;             // [2][64][64]  [p][k']
    float* XSS = smem + 8192;      // [2][64][64]  [p][c']

    const float* sb = sa + (size_t)nb * KK * PP;
    const float* xb = x + ((size_t)nb * CC + c0) * PP;
    const float* ib = inv_n + nb * PP;

    float acc[8][8] = {};
    float sv[8], xv[8];

#define PFV(i) { \
        const float* sp = sb + (size_t)krow * PP + ((i) << 6) + pcol8; \
        float4 s0 = *(const float4*)sp, s1 = *(const float4*)(sp + 4); \
        const float* xp = xb + (size_t)krow * PP + ((i) << 6) + pcol8; \
        float4 v0 = *(const float4*)xp, v1 = *(const float4*)(xp + 4); \
        const float* ip = ib + ((i) << 6) + pcol8; \
        float4 w0 = *(const float4*)ip, w1 = *(const float4*)(ip + 4); \
        sv[0]=s0.x; sv[1]=s0.y; sv[2]=s0.z; sv[3]=s0.w; \
        sv[4]=s1.x; sv[5]=s1.y; sv[6]=s1.z; sv[7]=s1.w; \
        xv[0]=v0.x*w0.x; xv[1]=v0.y*w0.y; xv[2]=v0.z*w0.z; xv[3]=v0.w*w0.w; \
        xv[4]=v1.x*w1.x; xv[5]=v1.y*w1.y; xv[6]=v1.z*w1.z; xv[7]=v1.w*w1.w; }

    PFV(0);
    for (int i = 0; i < 16; ++i) {
        __syncthreads();
        int bo = (i & 1) << 12;
        int kx = krow ^ (m << 3);
#pragma unroll
        for (int j = 0; j < 8; ++j) {
            SAS[bo + ((pcol8 + j) << 6) + kx] = sv[j];
            XSS[bo + ((pcol8 + j) << 6) + kx] = xv[j];
        }
        if (i < 15) { PFV(i + 1); }
        __syncthreads();
        const float* sr = SAS + bo + ((wv << 3) << 6) + ((ko << 3) ^ (wv << 3));
        const float* xr = XSS + bo + ((wv << 3) << 6) + ((co << 3) ^ (wv << 3));
#pragma unroll
        for (int jj = 0; jj < 8; ++jj) {
            float4 q0 = *(const float4*)(sr + (jj << 6));
            float4 q1 = *(const float4*)(sr + (jj << 6) + 4);
            float4 r0 = *(const float4*)(xr + (jj << 6));
            float4 r1 = *(const float4*)(xr + (jj << 6) + 4);
            float avv[8] = {q0.x, q0.y, q0.z, q0.w, q1.x, q1.y, q1.z, q1.w};
            float bw[8] = {r0.x, r0.y, r0.z, r0.w, r1.x, r1.y, r1.z, r1.w};
#pragma unroll
            for (int ii = 0; ii < 8; ++ii)
#pragma unroll
                for (int j = 0; j < 8; ++j)
                    acc[ii][j] = fmaf(avv[ii], bw[j], acc[ii][j]);
        }
    }
#undef PFV

#pragma unroll
    for (int s = 4; s >= 1; s >>= 1) {
        __syncthreads();
        if (wv >= s && wv < 2 * s) {
            float* rg = smem + (wv - s) * 4096 + lane * 2;
#pragma unroll
            for (int e = 0; e < 32; ++e)
                *(float2*)&rg[e * 128] =
                    make_float2(acc[e >> 2][(e & 3) * 2], acc[e >> 2][(e & 3) * 2 + 1]);
        }
        __syncthreads();
        if (wv < s) {
            const float* rg = smem + wv * 4096 + lane * 2;
#pragma unroll
            for (int e = 0; e < 32; ++e) {
                float2 v = *(const float2*)&rg[e * 128];
                acc[e >> 2][(e & 3) * 2] += v.x;
                acc[e >> 2][(e & 3) * 2 + 1] += v.y;
            }
        }
    }

    if (wv == 0) {
#pragma unroll
        for (int ii = 0; ii < 8; ++ii) {
            int k = (ko << 3) + ii;
            float sval = S[nb * KK + k];
            const float* cp = cent + (size_t)k * CC + c0 + (co << 3);
            float4 cv0 = *(const float4*)cp, cv1 = *(const float4*)(cp + 4);
            float4 o0 = make_float4(fmaf(-sval, cv0.x, acc[ii][0]),
                                    fmaf(-sval, cv0.y, acc[ii][1]),
                                    fmaf(-sval, cv0.z, acc[ii][2]),
                                    fmaf(-sval, cv0.w, acc[ii][3]));
            float4 o1 = make_float4(fmaf(-sval, cv1.x, acc[ii][4]),
                                    fmaf(-sval, cv1.y, acc[ii][5]),
                                    fmaf(-sval, cv1.z, acc[ii][6]),
                                    fmaf(-sval, cv1.w, acc[ii][7]));
            float* vp = vlad + ((size_t)nb * KK + k) * CC + c0 + (co << 3);
            *(float4*)vp = o0; *(float4*)(vp + 4) = o1;
        }
    }
}

// ---------------- per-row (n,k) sumsq + inv norm ----------------
__global__ void k_rownorm(const float* __restrict__ vlad, float* __restrict__ rinv,
                          float* __restrict__ rsq) {
    int r = blockIdx.x * 4 + (threadIdx.x >> 6);
    int lane = threadIdx.x & 63;
    const float* vp = vlad + (size_t)r * CC + lane;
    float s = 0.f;
#pragma unroll
    for (int i = 0; i < CC / 64; ++i) {
        float v = vp[i * 64];
        s = fmaf(v, v, s);
    }
#pragma unroll
    for (int off = 32; off > 0; off >>= 1) s += __shfl_xor(s, off);
    if (lane == 0) {
        float iv = 1.0f / fmaxf(sqrtf(s), EPS);
        rinv[r] = iv;
        rsq[r] = s * iv * iv;
    }
}

// ---------------- per-n total inverse norm ----------------
__global__ void k_tot(const float* __restrict__ rsq, float* __restrict__ tinv) {
    int n = blockIdx.x;
    int lane = threadIdx.x;   // 64 threads
    float s = rsq[n * KK + lane];
#pragma unroll
    for (int off = 32; off > 0; off >>= 1) s += __shfl_xor(s, off);
    if (lane == 0) tinv[n] = 1.0f / fmaxf(sqrtf(s), EPS);
}

// ---------------- final scale ----------------
__global__ void k_final(const float* __restrict__ vlad, const float* __restrict__ rinv,
                        const float* __restrict__ tinv, float* __restrict__ out) {
    size_t i4 = (size_t)blockIdx.x * 256 + threadIdx.x;   // over 262144 float4s
    float4 v = ((const float4*)vlad)[i4];
    int row = (int)(i4 >> 7);
    int n = row >> 6;
    float sc = rinv[row] * tinv[n];
    float4 o{v.x * sc, v.y * sc, v.z * sc, v.w * sc};
    ((float4*)out)[i4] = o;
}

extern "C" void kernel_launch(void* const* d_in, const int* in_sizes, int n_in,
                              void* d_out, int out_size, void* d_ws, size_t ws_size,
                              hipStream_t stream) {
    const float* x    = (const float*)d_in[0];
    const float* w    = (const float*)d_in[1];
    const float* bias = (const float*)d_in[2];
    const float* cent = (const float*)d_in[3];
    float* ws = (float*)d_ws;

    float* inv_n = ws;                          // 32768
    float* sa    = inv_n + NN * PP;             // 2097152
    float* S     = sa + (size_t)NN * KK * PP;   // 2048
    float* vlad  = S + NN * KK;                 // 1048576
    float* rinv  = vlad + (size_t)NN * KK * CC; // 2048
    float* rsq   = rinv + NN * KK;              // 2048
    float* tinv  = rsq + NN * KK;               // 32
    unsigned int* wpk = (unsigned int*)(tinv + NN);   // 16384 u32

    float* out = (float*)d_out;

    k_wprep<<<dim3(64), dim3(256), 0, stream>>>(w, wpk);
    k_logits<<<dim3(256), dim3(512), 0, stream>>>(x, wpk, bias, inv_n, sa);
    k_srow<<<dim3(NN * KK / 4), dim3(256), 0, stream>>>(sa, S);
    k_vlad<<<dim3(NN * 8), dim3(512), 0, stream>>>(x, sa, inv_n, S, cent, vlad);
    k_rownorm<<<dim3(NN * KK / 4), dim3(256), 0, stream>>>(vlad, rinv, rsq);
    k_tot<<<dim3(NN), dim3(64), 0, stream>>>(rsq, tinv);
    k_final<<<dim3(1024), dim3(256), 0, stream>>>(vlad, rinv, tinv, out);
}